// Round 6
// baseline (114.482 us; speedup 1.0000x reference)
//
#include <hip/hip_runtime.h>
#include <hip/hip_bf16.h>

#define BB 128
#define TT 1024
#define ENC_DIM 512
#define QUERY_DIM 1024
#define ATT_DIM 128
#define ATT_FILTERS 32
#define ATT_KERNEL 31
#define TILE_T 64
#define NTILE (TT / TILE_T)   // 16
#define TSPLIT 16
#define TCH (TT / TSPLIT)     // 64

using f32x4 = __attribute__((ext_vector_type(4))) float;

__device__ __forceinline__ float tanh_fast(float x) {
    float e = __expf(2.0f * x);
    return 1.0f - 2.0f * __builtin_amdgcn_rcpf(1.0f + e);
}

// K1: pq partials. grid (B, 2). h==1 blocks also zero ctx (stream-ordered
// before k_ctx's atomics).
__global__ __launch_bounds__(256) void k_pq(const float* __restrict__ query,
                                            const float* __restrict__ Wq,
                                            float* __restrict__ pqp,
                                            float* __restrict__ ctx) {
    __shared__ float q[512];
    __shared__ float pp[128];
    int b = blockIdx.x, h = blockIdx.y;
    int tid = threadIdx.x, a = tid & 127, ks = tid >> 7;
    if (h == 1) {
        ctx[b * ENC_DIM + tid] = 0.f;
        ctx[b * ENC_DIM + 256 + tid] = 0.f;
    }
    for (int i = tid; i < 512; i += 256) q[i] = query[b * QUERY_DIM + h * 512 + i];
    __syncthreads();
    const float* w  = Wq + (h * 512 + ks * 256) * ATT_DIM + a;
    const float* qs = q + ks * 256;
    float acc = 0.f;
#pragma unroll 16
    for (int k = 0; k < 256; ++k) acc += qs[k] * w[k * ATT_DIM];
    if (ks) pp[a] = acc;
    __syncthreads();
    if (!ks) pqp[(h * BB + b) * ATT_DIM + a] = acc + pp[a];
}

// K2: energies[b][t] = tanh(pq + conv(aw)@Wloc + pm) . v
// grid (NTILE, B). Lane owns a-pair (2*lane, 2*lane+1); pm 4 rows in flight.
__global__ __launch_bounds__(256, 4) void k_energy(
    const float* __restrict__ aw,    // (B,T,2)
    const float* __restrict__ ck,    // (31,2,32)
    const float* __restrict__ Wloc,  // (32,128)
    const float* __restrict__ pm,    // (B,T,128)
    const float* __restrict__ pqp,   // (2,B,128)
    const float* __restrict__ v,     // (128)
    float* __restrict__ energies)    // (B,T)
{
    __shared__ float s_aw[(TILE_T + 30) * 2];
    __shared__ float s_ck[ATT_KERNEL * 2 * ATT_FILTERS];
    __shared__ float s_f[TILE_T * ATT_FILTERS];

    int b = blockIdx.y;
    int t0 = blockIdx.x * TILE_T;
    int tid = threadIdx.x;

    for (int i = tid; i < ATT_KERNEL * 2 * ATT_FILTERS; i += 256) s_ck[i] = ck[i];
    for (int i = tid; i < (TILE_T + 30) * 2; i += 256) {
        int ii = i >> 1, c = i & 1;
        int t = t0 - 15 + ii;
        s_aw[i] = (t >= 0 && t < TT) ? aw[(b * TT + t) * 2 + c] : 0.f;
    }
    __syncthreads();

    {   // conv: filter j per thread, weights register-cached
        int j = tid & 31;
        float wk0[ATT_KERNEL], wk1[ATT_KERNEL];
#pragma unroll
        for (int k = 0; k < ATT_KERNEL; ++k) {
            wk0[k] = s_ck[k * 64 + j];
            wk1[k] = s_ck[k * 64 + 32 + j];
        }
        for (int t = tid >> 5; t < TILE_T; t += 8) {
            float acc0 = 0.f, acc1 = 0.f;
#pragma unroll
            for (int k = 0; k < ATT_KERNEL; ++k) {
                float2 awp = *reinterpret_cast<const float2*>(&s_aw[(t + k) * 2]);
                acc0 += awp.x * wk0[k];
                acc1 += awp.y * wk1[k];
            }
            s_f[t * ATT_FILTERS + j] = acc0 + acc1;
        }
    }
    __syncthreads();

    int w = tid >> 6, lane = tid & 63;
    int a = lane * 2;

    float2 wl[ATT_FILTERS];
#pragma unroll
    for (int j = 0; j < ATT_FILTERS; ++j)
        wl[j] = *reinterpret_cast<const float2*>(&Wloc[j * ATT_DIM + a]);
    float2 pqA = *reinterpret_cast<const float2*>(&pqp[b * ATT_DIM + a]);
    float2 pqB = *reinterpret_cast<const float2*>(&pqp[(BB + b) * ATT_DIM + a]);
    float pq0 = pqA.x + pqB.x, pq1 = pqA.y + pqB.y;
    float2 vv = *reinterpret_cast<const float2*>(&v[a]);

    const float* pmb = pm + ((long)(b * TT + t0)) * ATT_DIM + a;

    auto process = [&](int t, float2 c) {
        float x0 = pq0 + c.x;
        float x1 = pq1 + c.y;
        const float4* f4 = reinterpret_cast<const float4*>(&s_f[t * ATT_FILTERS]);
#pragma unroll
        for (int j4 = 0; j4 < ATT_FILTERS / 4; ++j4) {
            float4 f = f4[j4];
            x0 += f.x * wl[4 * j4].x     + f.y * wl[4 * j4 + 1].x
                + f.z * wl[4 * j4 + 2].x + f.w * wl[4 * j4 + 3].x;
            x1 += f.x * wl[4 * j4].y     + f.y * wl[4 * j4 + 1].y
                + f.z * wl[4 * j4 + 2].y + f.w * wl[4 * j4 + 3].y;
        }
        float e = tanh_fast(x0) * vv.x + tanh_fast(x1) * vv.y;
#pragma unroll
        for (int off = 32; off > 0; off >>= 1) e += __shfl_xor(e, off);
        if (lane == 0) energies[b * TT + t0 + t] = e;
    };

#pragma unroll
    for (int g = 0; g < 4; ++g) {   // 4 rows in flight per group
        int tg = w + g * 16;
        float2 c0 = *reinterpret_cast<const float2*>(&pmb[(tg)      * ATT_DIM]);
        float2 c1 = *reinterpret_cast<const float2*>(&pmb[(tg + 4)  * ATT_DIM]);
        float2 c2 = *reinterpret_cast<const float2*>(&pmb[(tg + 8)  * ATT_DIM]);
        float2 c3 = *reinterpret_cast<const float2*>(&pmb[(tg + 12) * ATT_DIM]);
        process(tg, c0);
        process(tg + 4, c1);
        process(tg + 8, c2);
        process(tg + 12, c3);
    }
}

// K3: softmax once per row, writes final weights. grid (B).
__global__ __launch_bounds__(256) void k_stats(const float* __restrict__ energies,
                                               float* __restrict__ wts) {
    __shared__ float red[4], red2[4];
    int b = blockIdx.x;
    int tid = threadIdx.x, w = tid >> 6, lane = tid & 63;
    float4 ev = reinterpret_cast<const float4*>(energies + b * TT)[tid];
    float m = fmaxf(fmaxf(ev.x, ev.y), fmaxf(ev.z, ev.w));
#pragma unroll
    for (int off = 32; off > 0; off >>= 1) m = fmaxf(m, __shfl_xor(m, off));
    if (lane == 0) red[w] = m;
    __syncthreads();
    m = fmaxf(fmaxf(red[0], red[1]), fmaxf(red[2], red[3]));
    float4 x;
    x.x = __expf(ev.x - m); x.y = __expf(ev.y - m);
    x.z = __expf(ev.z - m); x.w = __expf(ev.w - m);
    float s = x.x + x.y + x.z + x.w;
#pragma unroll
    for (int off = 32; off > 0; off >>= 1) s += __shfl_xor(s, off);
    if (lane == 0) red2[w] = s;
    __syncthreads();
    s = red2[0] + red2[1] + red2[2] + red2[3];
    float inv = 1.0f / s;
    x.x *= inv; x.y *= inv; x.z *= inv; x.w *= inv;
    reinterpret_cast<float4*>(wts + b * TT)[tid] = x;
}

// K4: slim partial context, atomic accumulate into ctx. grid (TSPLIT, B).
__global__ __launch_bounds__(256, 8) void k_ctx(
    const float* __restrict__ wts,   // (B,T) final weights
    const float* __restrict__ mem,   // (B,T,ENC)
    float* __restrict__ ctx)         // (B,ENC), zeroed by k_pq
{
    __shared__ float sw[TCH];
    __shared__ f32x4 sr[ENC_DIM / 4];
    int s = blockIdx.x, b = blockIdx.y;
    int tid = threadIdx.x;

    if (tid < TCH) sw[tid] = wts[b * TT + s * TCH + tid];
    __syncthreads();

    int p = tid >> 7, q = tid & 127;
    const f32x4* m4 = reinterpret_cast<const f32x4*>(mem + ((long)(b * TT + s * TCH)) * ENC_DIM) + q;
    f32x4 acc = {0.f, 0.f, 0.f, 0.f};
#pragma unroll 16
    for (int t = p; t < TCH; t += 2) {
        float wt = sw[t];
        f32x4 mv = m4[(long)t * (ENC_DIM / 4)];
        acc += wt * mv;
    }
    __syncthreads();
    if (p == 1) sr[q] = acc;
    __syncthreads();
    if (p == 0) {
        acc += sr[q];
        float* dst = ctx + b * ENC_DIM + 4 * q;
        atomicAdd(dst + 0, acc.x);
        atomicAdd(dst + 1, acc.y);
        atomicAdd(dst + 2, acc.z);
        atomicAdd(dst + 3, acc.w);
    }
}

extern "C" void kernel_launch(void* const* d_in, const int* in_sizes, int n_in,
                              void* d_out, int out_size, void* d_ws, size_t ws_size,
                              hipStream_t stream) {
    const float* query  = (const float*)d_in[0];
    const float* memory = (const float*)d_in[1];
    const float* pm     = (const float*)d_in[2];
    const float* awc    = (const float*)d_in[3];
    const float* Wq     = (const float*)d_in[4];
    const float* ck     = (const float*)d_in[5];
    const float* Wloc   = (const float*)d_in[6];
    const float* v      = (const float*)d_in[7];

    float* out = (float*)d_out;
    float* ctx = out;                       // (B, ENC_DIM)
    float* wts = out + BB * ENC_DIM;        // (B, T)

    float* pqp      = (float*)d_ws;                 // (2,B,128)
    float* energies = pqp + 2 * BB * ATT_DIM;       // (B,T)

    k_pq    <<<dim3(BB, 2),      dim3(256), 0, stream>>>(query, Wq, pqp, ctx);
    k_energy<<<dim3(NTILE, BB),  dim3(256), 0, stream>>>(awc, ck, Wloc, pm, pqp, v, energies);
    k_stats <<<dim3(BB),         dim3(256), 0, stream>>>(energies, wts);
    k_ctx   <<<dim3(TSPLIT, BB), dim3(256), 0, stream>>>(wts, memory, ctx);
}

// Round 7
// 110.460 us; speedup vs baseline: 1.0364x; 1.0364x over previous
//
#include <hip/hip_runtime.h>
#include <hip/hip_bf16.h>

#define BB 128
#define TT 1024
#define ENC_DIM 512
#define QUERY_DIM 1024
#define ATT_DIM 128
#define ATT_FILTERS 32
#define ATT_KERNEL 31
#define TILE_T 64
#define NTILE (TT / TILE_T)   // 16
#define TSPLIT 16
#define TCH (TT / TSPLIT)     // 64

using f32x4 = __attribute__((ext_vector_type(4))) float;

__device__ __forceinline__ float tanh_fast(float x) {
    float e = __expf(2.0f * x);
    return 1.0f - 2.0f * __builtin_amdgcn_rcpf(1.0f + e);
}

// K1: pq partials. grid (B, 2). h==1 blocks also zero ctx (stream-ordered
// before k_ctx's atomics).
__global__ __launch_bounds__(256) void k_pq(const float* __restrict__ query,
                                            const float* __restrict__ Wq,
                                            float* __restrict__ pqp,
                                            float* __restrict__ ctx) {
    __shared__ float q[512];
    __shared__ float pp[128];
    int b = blockIdx.x, h = blockIdx.y;
    int tid = threadIdx.x, a = tid & 127, ks = tid >> 7;
    if (h == 1) {
        ctx[b * ENC_DIM + tid] = 0.f;
        ctx[b * ENC_DIM + 256 + tid] = 0.f;
    }
    for (int i = tid; i < 512; i += 256) q[i] = query[b * QUERY_DIM + h * 512 + i];
    __syncthreads();
    const float* w  = Wq + (h * 512 + ks * 256) * ATT_DIM + a;
    const float* qs = q + ks * 256;
    float acc = 0.f;
#pragma unroll 16
    for (int k = 0; k < 256; ++k) acc += qs[k] * w[k * ATT_DIM];
    if (ks) pp[a] = acc;
    __syncthreads();
    if (!ks) pqp[(h * BB + b) * ATT_DIM + a] = acc + pp[a];
}

// K2: energies[b][t] = tanh(pq + conv(aw)@Wloc + pm) . v
// grid (NTILE, B). Lane owns a-pair (2*lane, 2*lane+1); pm 4 rows in flight.
__global__ __launch_bounds__(256, 4) void k_energy(
    const float* __restrict__ aw,    // (B,T,2)
    const float* __restrict__ ck,    // (31,2,32)
    const float* __restrict__ Wloc,  // (32,128)
    const float* __restrict__ pm,    // (B,T,128)
    const float* __restrict__ pqp,   // (2,B,128)
    const float* __restrict__ v,     // (128)
    float* __restrict__ energies)    // (B,T)
{
    __shared__ float s_aw[(TILE_T + 30) * 2];
    __shared__ float s_ck[ATT_KERNEL * 2 * ATT_FILTERS];
    __shared__ float s_f[TILE_T * ATT_FILTERS];

    int b = blockIdx.y;
    int t0 = blockIdx.x * TILE_T;
    int tid = threadIdx.x;

    for (int i = tid; i < ATT_KERNEL * 2 * ATT_FILTERS; i += 256) s_ck[i] = ck[i];
    for (int i = tid; i < (TILE_T + 30) * 2; i += 256) {
        int ii = i >> 1, c = i & 1;
        int t = t0 - 15 + ii;
        s_aw[i] = (t >= 0 && t < TT) ? aw[(b * TT + t) * 2 + c] : 0.f;
    }
    __syncthreads();

    {   // conv: filter j per thread, weights register-cached
        int j = tid & 31;
        float wk0[ATT_KERNEL], wk1[ATT_KERNEL];
#pragma unroll
        for (int k = 0; k < ATT_KERNEL; ++k) {
            wk0[k] = s_ck[k * 64 + j];
            wk1[k] = s_ck[k * 64 + 32 + j];
        }
        for (int t = tid >> 5; t < TILE_T; t += 8) {
            float acc0 = 0.f, acc1 = 0.f;
#pragma unroll
            for (int k = 0; k < ATT_KERNEL; ++k) {
                float2 awp = *reinterpret_cast<const float2*>(&s_aw[(t + k) * 2]);
                acc0 += awp.x * wk0[k];
                acc1 += awp.y * wk1[k];
            }
            s_f[t * ATT_FILTERS + j] = acc0 + acc1;
        }
    }
    __syncthreads();

    int w = tid >> 6, lane = tid & 63;
    int a = lane * 2;

    float2 wl[ATT_FILTERS];
#pragma unroll
    for (int j = 0; j < ATT_FILTERS; ++j)
        wl[j] = *reinterpret_cast<const float2*>(&Wloc[j * ATT_DIM + a]);
    float2 pqA = *reinterpret_cast<const float2*>(&pqp[b * ATT_DIM + a]);
    float2 pqB = *reinterpret_cast<const float2*>(&pqp[(BB + b) * ATT_DIM + a]);
    float pq0 = pqA.x + pqB.x, pq1 = pqA.y + pqB.y;
    float2 vv = *reinterpret_cast<const float2*>(&v[a]);

    const float* pmb = pm + ((long)(b * TT + t0)) * ATT_DIM + a;

    auto process = [&](int t, float2 c) {
        float x0 = pq0 + c.x;
        float x1 = pq1 + c.y;
        const float4* f4 = reinterpret_cast<const float4*>(&s_f[t * ATT_FILTERS]);
#pragma unroll
        for (int j4 = 0; j4 < ATT_FILTERS / 4; ++j4) {
            float4 f = f4[j4];
            x0 += f.x * wl[4 * j4].x     + f.y * wl[4 * j4 + 1].x
                + f.z * wl[4 * j4 + 2].x + f.w * wl[4 * j4 + 3].x;
            x1 += f.x * wl[4 * j4].y     + f.y * wl[4 * j4 + 1].y
                + f.z * wl[4 * j4 + 2].y + f.w * wl[4 * j4 + 3].y;
        }
        float e = tanh_fast(x0) * vv.x + tanh_fast(x1) * vv.y;
#pragma unroll
        for (int off = 32; off > 0; off >>= 1) e += __shfl_xor(e, off);
        if (lane == 0) energies[b * TT + t0 + t] = e;
    };

#pragma unroll
    for (int g = 0; g < 4; ++g) {   // 4 rows in flight per group
        int tg = w + g * 16;
        float2 c0 = *reinterpret_cast<const float2*>(&pmb[(tg)      * ATT_DIM]);
        float2 c1 = *reinterpret_cast<const float2*>(&pmb[(tg + 4)  * ATT_DIM]);
        float2 c2 = *reinterpret_cast<const float2*>(&pmb[(tg + 8)  * ATT_DIM]);
        float2 c3 = *reinterpret_cast<const float2*>(&pmb[(tg + 12) * ATT_DIM]);
        process(tg, c0);
        process(tg + 4, c1);
        process(tg + 8, c2);
        process(tg + 12, c3);
    }
}

// K3: softmax once per row, writes final weights. grid (B).
__global__ __launch_bounds__(256) void k_stats(const float* __restrict__ energies,
                                               float* __restrict__ wts) {
    __shared__ float red[4], red2[4];
    int b = blockIdx.x;
    int tid = threadIdx.x, w = tid >> 6, lane = tid & 63;
    float4 ev = reinterpret_cast<const float4*>(energies + b * TT)[tid];
    float m = fmaxf(fmaxf(ev.x, ev.y), fmaxf(ev.z, ev.w));
#pragma unroll
    for (int off = 32; off > 0; off >>= 1) m = fmaxf(m, __shfl_xor(m, off));
    if (lane == 0) red[w] = m;
    __syncthreads();
    m = fmaxf(fmaxf(red[0], red[1]), fmaxf(red[2], red[3]));
    float4 x;
    x.x = __expf(ev.x - m); x.y = __expf(ev.y - m);
    x.z = __expf(ev.z - m); x.w = __expf(ev.w - m);
    float s = x.x + x.y + x.z + x.w;
#pragma unroll
    for (int off = 32; off > 0; off >>= 1) s += __shfl_xor(s, off);
    if (lane == 0) red2[w] = s;
    __syncthreads();
    s = red2[0] + red2[1] + red2[2] + red2[3];
    float inv = 1.0f / s;
    x.x *= inv; x.y *= inv; x.z *= inv; x.w *= inv;
    reinterpret_cast<float4*>(wts + b * TT)[tid] = x;
}

// K4: slim partial context, atomic accumulate into ctx. grid (TSPLIT, B).
// NT loads on the memory stream ONLY: keeps the 64MB pm + small tensors
// L3-resident across graph replays while the 256MB stream bypasses.
__global__ __launch_bounds__(256, 8) void k_ctx(
    const float* __restrict__ wts,   // (B,T) final weights
    const float* __restrict__ mem,   // (B,T,ENC)
    float* __restrict__ ctx)         // (B,ENC), zeroed by k_pq
{
    __shared__ float sw[TCH];
    __shared__ f32x4 sr[ENC_DIM / 4];
    int s = blockIdx.x, b = blockIdx.y;
    int tid = threadIdx.x;

    if (tid < TCH) sw[tid] = wts[b * TT + s * TCH + tid];
    __syncthreads();

    int p = tid >> 7, q = tid & 127;
    const f32x4* m4 = reinterpret_cast<const f32x4*>(mem + ((long)(b * TT + s * TCH)) * ENC_DIM) + q;
    f32x4 acc = {0.f, 0.f, 0.f, 0.f};
#pragma unroll 16
    for (int t = p; t < TCH; t += 2) {
        float wt = sw[t];
        f32x4 mv = __builtin_nontemporal_load(&m4[(long)t * (ENC_DIM / 4)]);
        acc += wt * mv;
    }
    __syncthreads();
    if (p == 1) sr[q] = acc;
    __syncthreads();
    if (p == 0) {
        acc += sr[q];
        float* dst = ctx + b * ENC_DIM + 4 * q;
        atomicAdd(dst + 0, acc.x);
        atomicAdd(dst + 1, acc.y);
        atomicAdd(dst + 2, acc.z);
        atomicAdd(dst + 3, acc.w);
    }
}

extern "C" void kernel_launch(void* const* d_in, const int* in_sizes, int n_in,
                              void* d_out, int out_size, void* d_ws, size_t ws_size,
                              hipStream_t stream) {
    const float* query  = (const float*)d_in[0];
    const float* memory = (const float*)d_in[1];
    const float* pm     = (const float*)d_in[2];
    const float* awc    = (const float*)d_in[3];
    const float* Wq     = (const float*)d_in[4];
    const float* ck     = (const float*)d_in[5];
    const float* Wloc   = (const float*)d_in[6];
    const float* v      = (const float*)d_in[7];

    float* out = (float*)d_out;
    float* ctx = out;                       // (B, ENC_DIM)
    float* wts = out + BB * ENC_DIM;        // (B, T)

    float* pqp      = (float*)d_ws;                 // (2,B,128)
    float* energies = pqp + 2 * BB * ATT_DIM;       // (B,T)

    k_pq    <<<dim3(BB, 2),      dim3(256), 0, stream>>>(query, Wq, pqp, ctx);
    k_energy<<<dim3(NTILE, BB),  dim3(256), 0, stream>>>(awc, ck, Wloc, pm, pqp, v, energies);
    k_stats <<<dim3(BB),         dim3(256), 0, stream>>>(energies, wts);
    k_ctx   <<<dim3(TSPLIT, BB), dim3(256), 0, stream>>>(wts, memory, ctx);
}

// Round 8
// 93.923 us; speedup vs baseline: 1.2189x; 1.1761x over previous
//
#include <hip/hip_runtime.h>
#include <hip/hip_bf16.h>

#define BB 128
#define TT 1024
#define ENC_DIM 512
#define QUERY_DIM 1024
#define ATT_DIM 128
#define ATT_FILTERS 32
#define ATT_KERNEL 31
#define TILE_T 64
#define NTILE (TT / TILE_T)   // 16

using f32x4 = __attribute__((ext_vector_type(4))) float;

__device__ __forceinline__ float tanh_fast(float x) {
    float e = __expf(2.0f * x);
    return 1.0f - 2.0f * __builtin_amdgcn_rcpf(1.0f + e);
}

// K1: pq partials. grid (B, 2).
__global__ __launch_bounds__(256) void k_pq(const float* __restrict__ query,
                                            const float* __restrict__ Wq,
                                            float* __restrict__ pqp) {
    __shared__ float q[512];
    __shared__ float pp[128];
    int b = blockIdx.x, h = blockIdx.y;
    int tid = threadIdx.x, a = tid & 127, ks = tid >> 7;
    for (int i = tid; i < 512; i += 256) q[i] = query[b * QUERY_DIM + h * 512 + i];
    __syncthreads();
    const float* w  = Wq + (h * 512 + ks * 256) * ATT_DIM + a;
    const float* qs = q + ks * 256;
    float acc = 0.f;
#pragma unroll 16
    for (int k = 0; k < 256; ++k) acc += qs[k] * w[k * ATT_DIM];
    if (ks) pp[a] = acc;
    __syncthreads();
    if (!ks) pqp[(h * BB + b) * ATT_DIM + a] = acc + pp[a];
}

// K2: fused energies + chunk-local softmax + context partials.
// grid (NTILE, B). Writes energies (for k_final's wts), partP, partMS.
__global__ __launch_bounds__(256, 4) void k_fused(
    const float* __restrict__ aw,    // (B,T,2)
    const float* __restrict__ ck,    // (31,2,32)
    const float* __restrict__ Wloc,  // (32,128)
    const float* __restrict__ pm,    // (B,T,128)
    const float* __restrict__ pqp,   // (2,B,128)
    const float* __restrict__ v,     // (128)
    const float* __restrict__ mem,   // (B,T,ENC)
    float* __restrict__ energies,    // (B,T) ws
    float* __restrict__ partP,       // (NTILE,B,ENC) ws, unnormalized
    float* __restrict__ partMS)      // (NTILE,B,2) ws: {m_s, S_s}
{
    __shared__ float s_aw[(TILE_T + 30) * 2];
    __shared__ float s_ck[ATT_KERNEL * 2 * ATT_FILTERS];
    __shared__ float s_f[TILE_T * ATT_FILTERS];
    __shared__ float s_e[TILE_T];
    __shared__ float s_w[TILE_T];
    __shared__ f32x4 sr[ENC_DIM / 4];

    int s = blockIdx.x, b = blockIdx.y;
    int t0 = s * TILE_T;
    int tid = threadIdx.x;

    // ---- Phase A: conv + energies (identical math to prior k_energy) ----
    for (int i = tid; i < ATT_KERNEL * 2 * ATT_FILTERS; i += 256) s_ck[i] = ck[i];
    for (int i = tid; i < (TILE_T + 30) * 2; i += 256) {
        int ii = i >> 1, c = i & 1;
        int t = t0 - 15 + ii;
        s_aw[i] = (t >= 0 && t < TT) ? aw[(b * TT + t) * 2 + c] : 0.f;
    }
    __syncthreads();

    {   // conv: filter j per thread, weights register-cached
        int j = tid & 31;
        float wk0[ATT_KERNEL], wk1[ATT_KERNEL];
#pragma unroll
        for (int k = 0; k < ATT_KERNEL; ++k) {
            wk0[k] = s_ck[k * 64 + j];
            wk1[k] = s_ck[k * 64 + 32 + j];
        }
        for (int t = tid >> 5; t < TILE_T; t += 8) {
            float acc0 = 0.f, acc1 = 0.f;
#pragma unroll
            for (int k = 0; k < ATT_KERNEL; ++k) {
                float2 awp = *reinterpret_cast<const float2*>(&s_aw[(t + k) * 2]);
                acc0 += awp.x * wk0[k];
                acc1 += awp.y * wk1[k];
            }
            s_f[t * ATT_FILTERS + j] = acc0 + acc1;
        }
    }
    __syncthreads();

    {
        int w = tid >> 6, lane = tid & 63;
        int a = lane * 2;
        float2 wl[ATT_FILTERS];
#pragma unroll
        for (int j = 0; j < ATT_FILTERS; ++j)
            wl[j] = *reinterpret_cast<const float2*>(&Wloc[j * ATT_DIM + a]);
        float2 pqA = *reinterpret_cast<const float2*>(&pqp[b * ATT_DIM + a]);
        float2 pqB = *reinterpret_cast<const float2*>(&pqp[(BB + b) * ATT_DIM + a]);
        float pq0 = pqA.x + pqB.x, pq1 = pqA.y + pqB.y;
        float2 vv = *reinterpret_cast<const float2*>(&v[a]);
        const float* pmb = pm + ((long)(b * TT + t0)) * ATT_DIM + a;

        auto process = [&](int t, float2 c) {
            float x0 = pq0 + c.x;
            float x1 = pq1 + c.y;
            const float4* f4 = reinterpret_cast<const float4*>(&s_f[t * ATT_FILTERS]);
#pragma unroll
            for (int j4 = 0; j4 < ATT_FILTERS / 4; ++j4) {
                float4 f = f4[j4];
                x0 += f.x * wl[4 * j4].x     + f.y * wl[4 * j4 + 1].x
                    + f.z * wl[4 * j4 + 2].x + f.w * wl[4 * j4 + 3].x;
                x1 += f.x * wl[4 * j4].y     + f.y * wl[4 * j4 + 1].y
                    + f.z * wl[4 * j4 + 2].y + f.w * wl[4 * j4 + 3].y;
            }
            float e = tanh_fast(x0) * vv.x + tanh_fast(x1) * vv.y;
#pragma unroll
            for (int off = 32; off > 0; off >>= 1) e += __shfl_xor(e, off);
            if (lane == 0) {
                s_e[t] = e;
                energies[b * TT + t0 + t] = e;
            }
        };

#pragma unroll
        for (int g = 0; g < 4; ++g) {
            int tg = w + g * 16;
            float2 c0 = *reinterpret_cast<const float2*>(&pmb[(tg)      * ATT_DIM]);
            float2 c1 = *reinterpret_cast<const float2*>(&pmb[(tg + 4)  * ATT_DIM]);
            float2 c2 = *reinterpret_cast<const float2*>(&pmb[(tg + 8)  * ATT_DIM]);
            float2 c3 = *reinterpret_cast<const float2*>(&pmb[(tg + 12) * ATT_DIM]);
            process(tg, c0);
            process(tg + 4, c1);
            process(tg + 8, c2);
            process(tg + 12, c3);
        }
    }
    __syncthreads();

    // ---- Phase B: chunk-local softmax (unnormalized) ----
    float m_s = -1e30f;
#pragma unroll 8
    for (int t = 0; t < TILE_T; ++t) m_s = fmaxf(m_s, s_e[t]);
    if (tid < TILE_T) s_w[tid] = __expf(s_e[tid] - m_s);
    __syncthreads();
    if (tid == 0) {
        float S = 0.f;
#pragma unroll 8
        for (int t = 0; t < TILE_T; ++t) S += s_w[t];
        float2 msS = {m_s, S};
        *reinterpret_cast<float2*>(&partMS[(s * BB + b) * 2]) = msS;
    }

    // ---- Phase C: stream memory chunk with chunk-local weights ----
    int p = tid >> 7, q = tid & 127;
    const f32x4* m4 = reinterpret_cast<const f32x4*>(mem + ((long)(b * TT + t0)) * ENC_DIM) + q;
    f32x4 acc = {0.f, 0.f, 0.f, 0.f};
#pragma unroll 16
    for (int t = p; t < TILE_T; t += 2) {
        float wt = s_w[t];
        f32x4 mv = __builtin_nontemporal_load(&m4[(long)t * (ENC_DIM / 4)]);
        acc += wt * mv;
    }
    __syncthreads();
    if (p == 1) sr[q] = acc;
    __syncthreads();
    if (p == 0) {
        acc += sr[q];
        reinterpret_cast<f32x4*>(partP)[(s * BB + b) * (ENC_DIM / 4) + q] = acc;
    }
}

// K3: combine partials -> ctx, wts. grid (B).
__global__ __launch_bounds__(256) void k_final(
    const float* __restrict__ energies, // (B,T)
    const float* __restrict__ partP,    // (NTILE,B,ENC)
    const float* __restrict__ partMS,   // (NTILE,B,2)
    float* __restrict__ wts,            // (B,T) out
    float* __restrict__ ctx)            // (B,ENC) out
{
    int b = blockIdx.x;
    int tid = threadIdx.x;

    float ms[NTILE], Ss[NTILE];
#pragma unroll
    for (int s = 0; s < NTILE; ++s) {
        float2 v2 = *reinterpret_cast<const float2*>(&partMS[(s * BB + b) * 2]);
        ms[s] = v2.x; Ss[s] = v2.y;
    }
    float M = -1e30f;
#pragma unroll
    for (int s = 0; s < NTILE; ++s) M = fmaxf(M, ms[s]);
    float Ts[NTILE];
    float S = 0.f;
#pragma unroll
    for (int s = 0; s < NTILE; ++s) {
        Ts[s] = __expf(ms[s] - M);
        S += Ts[s] * Ss[s];
    }
    float invS = 1.0f / S;

    // weights: 1024 per row, 4 per thread
    float4 e = reinterpret_cast<const float4*>(energies + b * TT)[tid];
    float4 w;
    w.x = __expf(e.x - M) * invS;
    w.y = __expf(e.y - M) * invS;
    w.z = __expf(e.z - M) * invS;
    w.w = __expf(e.w - M) * invS;
    reinterpret_cast<float4*>(wts + b * TT)[tid] = w;

    // context: 512 per row, f32x4 per thread for tid<128
    if (tid < 128) {
        f32x4 acc = {0.f, 0.f, 0.f, 0.f};
#pragma unroll
        for (int s = 0; s < NTILE; ++s) {
            f32x4 pv = reinterpret_cast<const f32x4*>(partP)[(s * BB + b) * (ENC_DIM / 4) + tid];
            acc += Ts[s] * pv;
        }
        acc *= invS;
        reinterpret_cast<f32x4*>(ctx + b * ENC_DIM)[tid] = acc;
    }
}

extern "C" void kernel_launch(void* const* d_in, const int* in_sizes, int n_in,
                              void* d_out, int out_size, void* d_ws, size_t ws_size,
                              hipStream_t stream) {
    const float* query  = (const float*)d_in[0];
    const float* memory = (const float*)d_in[1];
    const float* pm     = (const float*)d_in[2];
    const float* awc    = (const float*)d_in[3];
    const float* Wq     = (const float*)d_in[4];
    const float* ck     = (const float*)d_in[5];
    const float* Wloc   = (const float*)d_in[6];
    const float* v      = (const float*)d_in[7];

    float* out = (float*)d_out;
    float* ctx = out;                       // (B, ENC_DIM)
    float* wts = out + BB * ENC_DIM;        // (B, T)

    float* pqp      = (float*)d_ws;                        // (2,B,128)
    float* energies = pqp + 2 * BB * ATT_DIM;              // (B,T)
    float* partP    = energies + BB * TT;                  // (NTILE,B,ENC)
    float* partMS   = partP + NTILE * BB * ENC_DIM;        // (NTILE,B,2)

    k_pq   <<<dim3(BB, 2),     dim3(256), 0, stream>>>(query, Wq, pqp);
    k_fused<<<dim3(NTILE, BB), dim3(256), 0, stream>>>(awc, ck, Wloc, pm, pqp, v,
                                                       memory, energies, partP, partMS);
    k_final<<<dim3(BB),        dim3(256), 0, stream>>>(energies, partP, partMS, wts, ctx);
}